// Round 3
// baseline (351.960 us; speedup 1.0000x reference)
//
#include <hip/hip_runtime.h>
#include <stdint.h>

#define BATCH   32
#define ROWS    4096
#define COLS    256
#define COL_IDX 5

typedef unsigned long long u64;
typedef unsigned int       u32;

// ---------------------------------------------------------------------------
// Kernel 1: extract column COL_IDX, pack into order-preserving u64 keys.
//   hi 32 = ~(order_preserving_uint(f))  -> ascending u64 == descending float
//   lo 32 = row index                    -> distinct keys, stable tie-break
// Side benefit: touches every 1 KB row of x -> warms LLC for the copy phase.
// ---------------------------------------------------------------------------
__global__ __launch_bounds__(256)
void extract_keys_kernel(const float* __restrict__ x, u64* __restrict__ keys) {
    const int i = blockIdx.x * 256 + threadIdx.x;      // 0 .. BATCH*ROWS-1
    u32 u = __float_as_uint(x[(size_t)i * COLS + COL_IDX]);
    u = (u >> 31) ? ~u : (u | 0x80000000u);            // order-preserving map
    u = ~u;                                            // descending
    keys[i] = ((u64)u << 32) | (u32)(i & (ROWS - 1));
}

// ---------------------------------------------------------------------------
// Kernel 2: rank-by-counting + fused row copy.
// One wave owns 64 consecutive source rows (one per lane). Rank of row i =
// #{j : packed[j] < packed[i]}.
// kb[j] is WAVE-UNIFORM -> compiler emits s_load (scalar pipe, free), so the
// inner step is just v_cmp_lt_u64 + v_addc = 2 VALU inst per 64 comparisons.
// Four accumulators break the addc dependency chain.
// Then the wave copies row r0+l -> out row rank[l]: one float4/lane = 1 KB/row.
// ---------------------------------------------------------------------------
__global__ __launch_bounds__(256)
void rank_copy_kernel(const float* __restrict__ x,
                      const u64* __restrict__ keys,
                      float* __restrict__ out) {
    const int wave = blockIdx.x * 4 + ((int)threadIdx.x >> 6);
    const int lane = (int)threadIdx.x & 63;
    const int b    = wave >> 6;                 // 64 waves per batch
    const int r0   = (wave & 63) << 6;          // first of this wave's 64 rows
    const u64* __restrict__ kb = keys + (size_t)b * ROWS;

    const u64 my = kb[r0 + lane];
    int a0 = 0, a1 = 0, a2 = 0, a3 = 0;
    #pragma unroll 4
    for (int j = 0; j < ROWS; j += 4) {
        a0 += (kb[j + 0] < my) ? 1 : 0;        // scalar load vs vector key
        a1 += (kb[j + 1] < my) ? 1 : 0;
        a2 += (kb[j + 2] < my) ? 1 : 0;
        a3 += (kb[j + 3] < my) ? 1 : 0;
    }
    const int rank = (a0 + a1) + (a2 + a3);

    // Copy 64 rows: row (r0+l) -> output row rank-of-(r0+l).
    const float4* __restrict__ src  =
        (const float4*)(x + ((size_t)b * ROWS + r0) * COLS);
    float4* __restrict__ outb = (float4*)(out + (size_t)b * ROWS * COLS);
    #pragma unroll 8
    for (int l = 0; l < 64; ++l) {
        const int dst = __builtin_amdgcn_readlane(rank, l);   // uniform
        outb[(size_t)dst * 64 + lane] = src[l * 64 + lane];
    }
}

extern "C" void kernel_launch(void* const* d_in, const int* in_sizes, int n_in,
                              void* d_out, int out_size, void* d_ws, size_t ws_size,
                              hipStream_t stream) {
    const float* x   = (const float*)d_in[0];
    float*       out = (float*)d_out;
    u64*         keys = (u64*)d_ws;            // BATCH*ROWS*8 = 1 MB scratch

    extract_keys_kernel<<<(BATCH * ROWS) / 256, 256, 0, stream>>>(x, keys);
    rank_copy_kernel<<<(BATCH * ROWS) / 256, 256, 0, stream>>>(x, keys, out);
}

// Round 4
// 248.525 us; speedup vs baseline: 1.4162x; 1.4162x over previous
//
#include <hip/hip_runtime.h>
#include <stdint.h>

#define BATCH   32
#define ROWS    4096
#define COLS    256
#define COL_IDX 5

typedef unsigned long long u64;
typedef unsigned int       u32;

// ---------------------------------------------------------------------------
// Kernel 1: extract column COL_IDX, pack into order-preserving u64 keys.
//   hi 32 = ~(order_preserving_uint(f))  -> ascending u64 == descending float
//   lo 32 = row index                    -> distinct keys, stable tie-break
// ---------------------------------------------------------------------------
__global__ __launch_bounds__(256)
void extract_keys_kernel(const float* __restrict__ x, u64* __restrict__ keys) {
    const int i = blockIdx.x * 256 + threadIdx.x;      // 0 .. BATCH*ROWS-1
    u32 u = __float_as_uint(x[(size_t)i * COLS + COL_IDX]);
    u = (u >> 31) ? ~u : (u | 0x80000000u);            // order-preserving map
    u = ~u;                                            // descending
    keys[i] = ((u64)u << 32) | (u32)(i & (ROWS - 1));
}

// ---------------------------------------------------------------------------
// Kernel 2: rank-by-counting + fused row copy, 4-way wave-split per block.
// Block owns 64 consecutive rows (lane l <-> row r0+l). Each of the block's
// 4 waves counts #{j in its 1024-key quarter : key_j < key_i} with the
// readlane-broadcast compare (operands stay in registers — R2 showed scalar
// loads stall on lgkmcnt). Partials combine via 1 KB LDS. Grid = 2048 blocks
// = 8 waves/SIMD so the readlane->cmp dependency chain is hidden by TLP.
// Then each wave copies 16 of the 64 rows (float4/lane = 1 KB/row).
// ---------------------------------------------------------------------------
__global__ __launch_bounds__(256, 8)
void rank_copy_kernel(const float* __restrict__ x,
                      const u64* __restrict__ keys,
                      float* __restrict__ out) {
    __shared__ int part[4][64];
    const int w    = (int)threadIdx.x >> 6;     // wave in block (0..3)
    const int lane = (int)threadIdx.x & 63;
    const int b    = blockIdx.x >> 6;           // 64 blocks per batch
    const int r0   = (blockIdx.x & 63) << 6;    // block's first row
    const u64* __restrict__ kb = keys + (size_t)b * ROWS;

    const u64 my = kb[r0 + lane];
    int rank = 0;
    const int jbeg = w * (ROWS / 4);
    for (int j0 = jbeg; j0 < jbeg + ROWS / 4; j0 += 64) {
        const u64 kv = kb[j0 + lane];           // 64 keys, coalesced
        const u32 lo = (u32)kv, hi = (u32)(kv >> 32);
        #pragma unroll
        for (int l = 0; l < 64; ++l) {
            const u32 klo = (u32)__builtin_amdgcn_readlane(lo, l);
            const u32 khi = (u32)__builtin_amdgcn_readlane(hi, l);
            const u64 kk  = ((u64)khi << 32) | klo;
            rank += (kk < my) ? 1 : 0;
        }
    }
    part[w][lane] = rank;
    __syncthreads();
    const int total = part[0][lane] + part[1][lane]
                    + part[2][lane] + part[3][lane];

    // Copy 64 rows; wave w handles rows [w*16, w*16+16).
    const float4* __restrict__ src  =
        (const float4*)(x + ((size_t)b * ROWS + r0) * COLS);
    float4* __restrict__ outb = (float4*)(out + (size_t)b * ROWS * COLS);
    #pragma unroll 4
    for (int t = 0; t < 16; ++t) {
        const int l   = w * 16 + t;
        const int dst = __builtin_amdgcn_readlane(total, l);   // uniform
        outb[(size_t)dst * 64 + lane] = src[(size_t)l * 64 + lane];
    }
}

extern "C" void kernel_launch(void* const* d_in, const int* in_sizes, int n_in,
                              void* d_out, int out_size, void* d_ws, size_t ws_size,
                              hipStream_t stream) {
    const float* x   = (const float*)d_in[0];
    float*       out = (float*)d_out;
    u64*         keys = (u64*)d_ws;            // BATCH*ROWS*8 = 1 MB scratch

    extract_keys_kernel<<<(BATCH * ROWS) / 256, 256, 0, stream>>>(x, keys);
    rank_copy_kernel<<<BATCH * 64, 256, 0, stream>>>(x, keys, out);
}